// Round 1
// baseline (997.094 us; speedup 1.0000x reference)
//
#include <hip/hip_runtime.h>
#include <hip/hip_bf16.h>
#include <cstdint>
#include <cstddef>

// Shapes fixed by the problem
#define BATCH 2
#define SEQ 2048
#define NH 16
#define DH 64
#define DM 1024
#define MTOT 4096  // BATCH*SEQ

typedef __attribute__((ext_vector_type(8))) short short8;
typedef __attribute__((ext_vector_type(4))) float f32x4;

#define MFMA16(a, b, c) __builtin_amdgcn_mfma_f32_16x16x32_bf16((a), (b), (c), 0, 0, 0)

__device__ __forceinline__ unsigned short f2bf(float f) {
  unsigned int u = __builtin_bit_cast(unsigned int, f);
  u += 0x7fffu + ((u >> 16) & 1u);   // RNE; inputs are finite
  return (unsigned short)(u >> 16);
}

// ---------------- input cast: q,k,v fp32 -> bf16 ----------------
__global__ __launch_bounds__(256) void cvt_x(const float* __restrict__ q,
                                             const float* __restrict__ k,
                                             const float* __restrict__ v,
                                             unsigned short* __restrict__ dst) {
  const float* srcs[3] = {q, k, v};
  const float* s = srcs[blockIdx.y];
  unsigned short* d = dst + (size_t)blockIdx.y * (MTOT * DM);
  int i = blockIdx.x * 256 + threadIdx.x;
  if (i < (MTOT * DM / 4)) {
    float4 f = ((const float4*)s)[i];
    ushort4 o;
    o.x = f2bf(f.x); o.y = f2bf(f.y); o.z = f2bf(f.z); o.w = f2bf(f.w);
    ((ushort4*)d)[i] = o;
  }
}

// ---------------- weight cast + transpose: W[k][n] -> WT[n][k] bf16 ----------------
__global__ __launch_bounds__(256) void cvt_w(const float* __restrict__ w0,
                                             const float* __restrict__ w1,
                                             const float* __restrict__ w2,
                                             const float* __restrict__ w3,
                                             unsigned short* __restrict__ dst) {
  const float* srcs[4] = {w0, w1, w2, w3};
  const float* src = srcs[blockIdx.z];
  unsigned short* d = dst + (size_t)blockIdx.z * (DM * DM);
  __shared__ float t[32][33];
  int tx = threadIdx.x & 31, ty = threadIdx.x >> 5;  // ty 0..7
  int k0 = blockIdx.y * 32, n0 = blockIdx.x * 32;
#pragma unroll
  for (int r = 0; r < 32; r += 8) t[ty + r][tx] = src[(k0 + ty + r) * DM + n0 + tx];
  __syncthreads();
#pragma unroll
  for (int r = 0; r < 32; r += 8) d[(n0 + ty + r) * DM + k0 + tx] = f2bf(t[tx][ty + r]);
}

// ---------------- 128x128 bf16 MFMA GEMM: C[m,n] = sum_k A[m,k]*Bt[n,k] + bias[n] ----------------
// MODE 0: write bf16 head layout   Q/K: dst[((b*16+h)*2048 + s)*64 + d]
// MODE 1: write bf16 head-T layout V:   dst[((b*16+h)*64 + d)*2048 + s]
// MODE 2: write fp32 plain [m*1024+n]
template <int MODE>
__global__ __launch_bounds__(256) void gemm128(const unsigned short* __restrict__ A,
                                               const unsigned short* __restrict__ Bt,
                                               const float* __restrict__ bias,
                                               void* __restrict__ out) {
  __shared__ unsigned short As[128 * 32];
  __shared__ unsigned short Bs[128 * 32];
  int tid = threadIdx.x, lane = tid & 63;
  int w = tid >> 6, wm = (w >> 1) * 64, wn = (w & 1) * 64;
  int quad = lane >> 4, l15 = lane & 15;
  int m0 = blockIdx.x * 128, n0 = blockIdx.y * 128;
  f32x4 acc[4][4] = {};

  int r0 = tid >> 2;          // 0..63
  int c0 = (tid & 3) * 8;     // ushort col within 32-wide K slab
  const uint4* ga0 = (const uint4*)(A + (size_t)(m0 + r0) * DM + c0);
  const uint4* ga1 = (const uint4*)(A + (size_t)(m0 + 64 + r0) * DM + c0);
  const uint4* gb0 = (const uint4*)(Bt + (size_t)(n0 + r0) * DM + c0);
  const uint4* gb1 = (const uint4*)(Bt + (size_t)(n0 + 64 + r0) * DM + c0);

  for (int k0 = 0; k0 < DM; k0 += 32) {
    uint4 va0 = ga0[k0 >> 3];
    uint4 va1 = ga1[k0 >> 3];
    uint4 vb0 = gb0[k0 >> 3];
    uint4 vb1 = gb1[k0 >> 3];
    __syncthreads();
    *(uint4*)(As + tid * 8) = va0;
    *(uint4*)(As + 2048 + tid * 8) = va1;
    *(uint4*)(Bs + tid * 8) = vb0;
    *(uint4*)(Bs + 2048 + tid * 8) = vb1;
    __syncthreads();
    short8 af[4], bfr[4];
#pragma unroll
    for (int t = 0; t < 4; t++) {
      af[t] = *(const short8*)(As + (wm + t * 16 + l15) * 32 + quad * 8);
      bfr[t] = *(const short8*)(Bs + (wn + t * 16 + l15) * 32 + quad * 8);
    }
#pragma unroll
    for (int i = 0; i < 4; i++)
#pragma unroll
      for (int j = 0; j < 4; j++) acc[i][j] = MFMA16(af[i], bfr[j], acc[i][j]);
  }

  float bvals[4];
#pragma unroll
  for (int j = 0; j < 4; j++) bvals[j] = bias[n0 + wn + j * 16 + l15];
#pragma unroll
  for (int i = 0; i < 4; i++) {
#pragma unroll
    for (int j = 0; j < 4; j++) {
#pragma unroll
      for (int r = 0; r < 4; r++) {
        int m = m0 + wm + i * 16 + quad * 4 + r;
        int n = n0 + wn + j * 16 + l15;
        float v = acc[i][j][r] + bvals[j];
        if (MODE == 0) {
          unsigned short* dq = (unsigned short*)out;
          dq[(((size_t)((m >> 11) * 16 + (n >> 6)) * SEQ + (m & 2047)) * DH) + (n & 63)] = f2bf(v);
        } else if (MODE == 1) {
          unsigned short* dq = (unsigned short*)out;
          dq[(((size_t)((m >> 11) * 16 + (n >> 6)) * DH + (n & 63)) * SEQ) + (m & 2047)] = f2bf(v);
        } else {
          ((float*)out)[(size_t)m * DM + n] = v;
        }
      }
    }
  }
}

// ---------------- fused attention ----------------
// grid (32 = B*H, 32 = SEQ/64); block 256 (4 waves, 16 Q-rows each).
// Loop 1: row sums of exp(s). Loop 2: recompute s, write attn=exp(s)/l fp32 to d_out,
// LDS-transpose P tile into MFMA A layout, PV accumulate; write ctx bf16 [M, DM].
__global__ __launch_bounds__(256) void attn_fused(const unsigned short* __restrict__ Qh,
                                                  const unsigned short* __restrict__ Kh,
                                                  const unsigned short* __restrict__ VhT,
                                                  float* __restrict__ attn_out,
                                                  unsigned short* __restrict__ ctx) {
  int bh = blockIdx.x;
  int q0 = blockIdx.y * 64;
  int tid = threadIdx.x, w = tid >> 6, lane = tid & 63;
  int quad = lane >> 4, l15 = lane & 15;
  int qrow = q0 + w * 16;
  const unsigned short* Qb = Qh + ((size_t)bh * SEQ + qrow) * DH;
  const unsigned short* Kb = Kh + (size_t)bh * SEQ * DH;
  const unsigned short* Vb = VhT + (size_t)bh * DH * SEQ;

  short8 aq0 = *(const short8*)(Qb + l15 * DH + quad * 8);
  short8 aq1 = *(const short8*)(Qb + l15 * DH + 32 + quad * 8);

  // ---- pass 1: row sums of exp(scores) ----
  float part[4] = {0.f, 0.f, 0.f, 0.f};
  for (int kt = 0; kt < SEQ; kt += 16) {
    const unsigned short* kp = Kb + (size_t)(kt + l15) * DH + quad * 8;
    short8 bk0 = *(const short8*)(kp);
    short8 bk1 = *(const short8*)(kp + 32);
    f32x4 s = {0.f, 0.f, 0.f, 0.f};
    s = MFMA16(aq0, bk0, s);
    s = MFMA16(aq1, bk1, s);
#pragma unroll
    for (int r = 0; r < 4; r++) part[r] += __expf(s[r] * 0.125f);
  }
#pragma unroll
  for (int off = 1; off < 16; off <<= 1) {
#pragma unroll
    for (int r = 0; r < 4; r++) part[r] += __shfl_xor(part[r], off, 64);
  }
  float inv[4];
#pragma unroll
  for (int r = 0; r < 4; r++) inv[r] = 1.0f / part[r];

  // ---- pass 2: attn write + PV ----
  __shared__ unsigned short plds[4][16 * 40];  // per-wave 16x32 P tile, row stride 40 (80B, 16B-aligned)
  unsigned short* pl = &plds[w][0];
  f32x4 cacc[4] = {};
  float* arow = attn_out + ((size_t)bh * SEQ + qrow) * SEQ;

  for (int kt = 0; kt < SEQ; kt += 32) {
#pragma unroll
    for (int t = 0; t < 2; t++) {
      int kc = kt + t * 16;
      const unsigned short* kp = Kb + (size_t)(kc + l15) * DH + quad * 8;
      short8 bk0 = *(const short8*)(kp);
      short8 bk1 = *(const short8*)(kp + 32);
      f32x4 s = {0.f, 0.f, 0.f, 0.f};
      s = MFMA16(aq0, bk0, s);
      s = MFMA16(aq1, bk1, s);
#pragma unroll
      for (int r = 0; r < 4; r++) {
        float p = __expf(s[r] * 0.125f) * inv[r];
        arow[(size_t)(quad * 4 + r) * SEQ + kc + l15] = p;
        pl[(quad * 4 + r) * 40 + t * 16 + l15] = f2bf(p);
      }
    }
    // same-wave DS ordering: writes above are visible to the b128 read below
    short8 pa = *(const short8*)(pl + l15 * 40 + quad * 8);
#pragma unroll
    for (int dt = 0; dt < 4; dt++) {
      short8 bv = *(const short8*)(Vb + (size_t)(dt * 16 + l15) * SEQ + kt + quad * 8);
      cacc[dt] = MFMA16(pa, bv, cacc[dt]);
    }
  }

  int b = bh >> 4, h = bh & 15;
#pragma unroll
  for (int dt = 0; dt < 4; dt++) {
#pragma unroll
    for (int r = 0; r < 4; r++) {
      int m = b * SEQ + qrow + quad * 4 + r;
      int c = h * DH + dt * 16 + l15;
      ctx[(size_t)m * DM + c] = f2bf(cacc[dt][r]);
    }
  }
}

// ---------------- host launch ----------------
extern "C" void kernel_launch(void* const* d_in, const int* in_sizes, int n_in,
                              void* d_out, int out_size, void* d_ws, size_t ws_size,
                              hipStream_t stream) {
  const float* q  = (const float*)d_in[0];
  const float* k  = (const float*)d_in[1];
  const float* v  = (const float*)d_in[2];
  // d_in[3] = mask: accepted but unused (as in reference)
  const float* wq = (const float*)d_in[4];
  const float* bq = (const float*)d_in[5];
  const float* wk = (const float*)d_in[6];
  const float* bk = (const float*)d_in[7];
  const float* wv = (const float*)d_in[8];
  const float* bv = (const float*)d_in[9];
  const float* wo = (const float*)d_in[10];
  const float* bo = (const float*)d_in[11];

  char* ws = (char*)d_ws;
  // ws layout (bytes):
  //   0        : xb   (q,k,v bf16)   3 * 8 MB
  //   24 MB    : wT   (4 transposed bf16 weights) 4 * 2 MB
  //   32 MB    : QH   bf16 [BH,S,64]  8 MB
  //   40 MB    : KH   bf16 [BH,S,64]  8 MB
  //   48 MB    : VT   bf16 [BH,64,S]  8 MB
  //   56 MB    : CTX  bf16 [M,DM]     8 MB      -> total 64 MB
  unsigned short* xb  = (unsigned short*)(ws);
  unsigned short* wT  = (unsigned short*)(ws + (size_t)24 * 1024 * 1024);
  unsigned short* QH  = (unsigned short*)(ws + (size_t)32 * 1024 * 1024);
  unsigned short* KH  = (unsigned short*)(ws + (size_t)40 * 1024 * 1024);
  unsigned short* VT  = (unsigned short*)(ws + (size_t)48 * 1024 * 1024);
  unsigned short* CTX = (unsigned short*)(ws + (size_t)56 * 1024 * 1024);

  float* out_proj = (float*)d_out;                       // [B,S,DM] = 4,194,304 floats
  float* attn_out = (float*)d_out + (size_t)MTOT * DM;   // [B,H,S,S] = 134,217,728 floats

  cvt_x<<<dim3(MTOT * DM / 4 / 256, 3), 256, 0, stream>>>(q, k, v, xb);
  cvt_w<<<dim3(32, 32, 4), 256, 0, stream>>>(wq, wk, wv, wo, wT);

  // projections: Q,K -> head layout; V -> transposed head layout
  gemm128<0><<<dim3(32, 8), 256, 0, stream>>>(xb, wT, bq, QH);
  gemm128<0><<<dim3(32, 8), 256, 0, stream>>>(xb + (size_t)MTOT * DM, wT + (size_t)DM * DM, bk, KH);
  gemm128<1><<<dim3(32, 8), 256, 0, stream>>>(xb + (size_t)2 * MTOT * DM, wT + (size_t)2 * DM * DM, bv, VT);

  attn_fused<<<dim3(BATCH * NH, SEQ / 64), 256, 0, stream>>>(QH, KH, VT, attn_out, CTX);

  // output projection -> fp32 d_out
  gemm128<2><<<dim3(32, 8), 256, 0, stream>>>(CTX, wT + (size_t)3 * DM * DM, bo, out_proj);
}